// Round 11
// baseline (837.670 us; speedup 1.0000x reference)
//
#include <hip/hip_runtime.h>
#include <cmath>

#define TT 256
#define BB 512
#define DD 128
#define HH 128
#define NCOL 528   // 4*H + 16 quantum-angle cols
#define KK 256
#define NCPAD 576  // 9 * 64

// ---------------- weight pack ----------------
// Wxp[528][128]                 : x-half row-major (xgemm staging)
// Whr3 float4[j][t] (j=g*8+k4)  : h-half main cols; thread t=h*4+ks owns cols
//                                 {g*128+h, g=0..3}, k-seg ks (32 k each)
// Whql[16][128]                 : h-half quantum cols (per-task regs in rec)
// bcat[576]
__global__ __launch_bounds__(256) void pack_weights(
    const float* __restrict__ Wf, const float* __restrict__ bf,
    const float* __restrict__ Wfq, const float* __restrict__ bfq,
    const float* __restrict__ Wi, const float* __restrict__ bi,
    const float* __restrict__ Wiq, const float* __restrict__ biq,
    const float* __restrict__ Wg, const float* __restrict__ bg,
    const float* __restrict__ Wgq, const float* __restrict__ bgq,
    const float* __restrict__ Wo, const float* __restrict__ bo,
    const float* __restrict__ Woq, const float* __restrict__ boq,
    float* __restrict__ Wxp, float* __restrict__ Whr3,
    float* __restrict__ Whql, float* __restrict__ bcat)
{
    int idx = blockIdx.x * blockDim.x + threadIdx.x;
    if (idx < NCOL * KK) {
        int c = idx >> 8, k = idx & 255;
        const float* srcW; int cl;
        if (c < 512) { int g = c >> 7; cl = c & 127;
            srcW = (g == 0) ? Wf : (g == 1) ? Wi : (g == 2) ? Wg : Wo; }
        else { int g = (c - 512) >> 2; cl = (c - 512) & 3;
            srcW = (g == 0) ? Wfq : (g == 1) ? Wiq : (g == 2) ? Wgq : Woq; }
        float v = srcW[(size_t)cl * KK + k];
        if (k < 128) Wxp[(size_t)c * 128 + k] = v;
        else {
            int kk = k - 128;
            if (c < 512) {
                int gate = c >> 7, hcol = c & 127;
                int t = hcol * 4 + (kk >> 5);
                int j = gate * 8 + ((kk >> 2) & 7);
                Whr3[((size_t)j * 512 + t) * 4 + (kk & 3)] = v;
            } else {
                Whql[(size_t)(c - 512) * 128 + kk] = v;
            }
        }
    }
    if (idx < NCPAD) {
        float b = 0.f;
        int c = idx;
        if (c < 512) { int g = c >> 7; int cl = c & 127;
            b = (g == 0) ? bf[cl] : (g == 1) ? bi[cl] : (g == 2) ? bg[cl] : bo[cl]; }
        else if (c < NCOL) { int g = (c - 512) >> 2; int cl = (c - 512) & 3;
            b = (g == 0) ? bfq[cl] : (g == 1) ? biq[cl] : (g == 2) ? bgq[cl] : boq[cl]; }
        bcat[c] = b;
    }
}

// ---------------- phase 1: Zx = X @ Wx^T + bcat  (M x 528, K=128) ----------------
#define P1_BM 128
#define P1_BN 64
#define ATP 132
#define BTP 68
__global__ __launch_bounds__(256, 3) void xgemm(
    const float* __restrict__ X, const float* __restrict__ Wxp,
    const float* __restrict__ bcat, float* __restrict__ Zx)
{
    __shared__ float At[64][ATP];
    __shared__ float Bt[64][BTP];
    const int tid = threadIdx.x;
    const int m0 = blockIdx.x * P1_BM;
    const int c0 = blockIdx.y * P1_BN;
    const int tm = tid >> 3;
    const int tn = tid & 7;
    float acc[4][8] = {};

    for (int khf = 0; khf < 2; ++khf) {
        #pragma unroll
        for (int j = 0; j < 8; ++j) {
            int fidx = tid + 256 * j;
            int m = fidx >> 4, k4 = (fidx & 15) * 4;
            float4 v = *(const float4*)(X + (size_t)(m0 + m) * 128 + khf * 64 + k4);
            At[k4 + 0][m] = v.x; At[k4 + 1][m] = v.y; At[k4 + 2][m] = v.z; At[k4 + 3][m] = v.w;
        }
        #pragma unroll
        for (int j = 0; j < 4; ++j) {
            int fidx = tid + 256 * j;
            int c = fidx >> 4, k4 = (fidx & 15) * 4;
            int cg = c0 + c;
            float4 v = make_float4(0.f, 0.f, 0.f, 0.f);
            if (cg < NCOL) v = *(const float4*)(Wxp + (size_t)cg * 128 + khf * 64 + k4);
            Bt[k4 + 0][c] = v.x; Bt[k4 + 1][c] = v.y; Bt[k4 + 2][c] = v.z; Bt[k4 + 3][c] = v.w;
        }
        __syncthreads();
        #pragma unroll 4
        for (int k = 0; k < 64; ++k) {
            float4 a  = *(const float4*)&At[k][tm * 4];
            float4 b0 = *(const float4*)&Bt[k][tn * 8];
            float4 b1 = *(const float4*)&Bt[k][tn * 8 + 4];
            float av[4] = {a.x, a.y, a.z, a.w};
            float bv[8] = {b0.x, b0.y, b0.z, b0.w, b1.x, b1.y, b1.z, b1.w};
            #pragma unroll
            for (int i = 0; i < 4; ++i)
                #pragma unroll
                for (int j = 0; j < 8; ++j)
                    acc[i][j] = fmaf(av[i], bv[j], acc[i][j]);
        }
        __syncthreads();
    }
    int c = c0 + tn * 8;
    if (c < NCOL) {
        float4 ba = *(const float4*)(bcat + c);
        float4 bb = *(const float4*)(bcat + c + 4);
        #pragma unroll
        for (int i = 0; i < 4; ++i) {
            int m = m0 + tm * 4 + i;
            float4 o0, o1;
            o0.x = acc[i][0] + ba.x; o0.y = acc[i][1] + ba.y;
            o0.z = acc[i][2] + ba.z; o0.w = acc[i][3] + ba.w;
            o1.x = acc[i][4] + bb.x; o1.y = acc[i][5] + bb.y;
            o1.z = acc[i][6] + bb.z; o1.w = acc[i][7] + bb.w;
            *(float4*)(Zx + (size_t)m * NCOL + c)     = o0;
            *(float4*)(Zx + (size_t)m * NCOL + c + 4) = o1;
        }
    }
}

// ---------------- phase 2: recurrence ----------------
__device__ __forceinline__ float sigm(float x) { return 1.0f / (1.0f + __expf(-x)); }
__device__ __forceinline__ float tanh_f(float x) {
    float e = __expf(2.f * x);
    return 1.f - 2.f / (e + 1.f);
}

// packed fp32 FMA: acc.xy += a.xy * b.xy. All-"v" constraints force arch-VGPR
// residency for the weight operand (AGPR placement would cost a copy per use).
__device__ __forceinline__ void pkfma(float2 &acc, const float2 &a, const float2 &b) {
    asm("v_pk_fma_f32 %0, %1, %2, %0" : "+v"(acc) : "v"(a), "v"(b));
}

// in-quad allreduce via DPP quad_perm: 0xB1 = xor1, 0x4E = xor2
#define DPPRED(v) { \
    v += __int_as_float(__builtin_amdgcn_update_dpp(0, __float_as_int(v), 0xB1, 0xF, 0xF, true)); \
    v += __int_as_float(__builtin_amdgcn_update_dpp(0, __float_as_int(v), 0x4E, 0xF, 0xF, true)); }

// skewed h index: the 4 k-segments land on distinct bank quads
__device__ __forceinline__ int hsk(int k) { return k + 8 * (k >> 5); }  // max 151

// 512 threads; waves_per_eu(2,2): 256-VGPR cap.
__global__ __launch_bounds__(512)
__attribute__((amdgpu_waves_per_eu(2, 2)))
void qlstm_rec(
    const float* __restrict__ Zx,      // [TC][512][528]
    const float* __restrict__ Whr3,    // float4 [32][512]
    const float* __restrict__ Whql,    // [16][128]
    const float* __restrict__ hx0, const float* __restrict__ cx0,
    float* __restrict__ stateH, float* __restrict__ stateC,
    const float* __restrict__ Wq, const float* __restrict__ bq,
    const float* __restrict__ thf, const float* __restrict__ thi,
    const float* __restrict__ thg, const float* __restrict__ tho,
    float* __restrict__ out, int t0, int TC)
{
    __shared__ __align__(16) float hL[2][152];     // skewed
    __shared__ __align__(16) float cEd[2][20];     // per (r,qc): d = (w<3 ? cos(th_w)*c : cos(a3+th3))
    __shared__ __align__(16) float cEc[2][20];     // per (r,qc): raw c = cos(a)

    const int tid  = threadIdx.x;
    const int row0 = blockIdx.x * 2;
    const int ks   = tid & 3;        // k-segment (32 k each)
    const int h    = tid >> 2;       // 0..127: this thread's h column

    // ---- main weights into registers as float2 pairs (128 regs), coalesced f4 loads ----
    const float4* Wp3 = (const float4*)Whr3;
    float2 wv2[64];
    #pragma unroll
    for (int j = 0; j < 32; ++j) {
        float4 t = Wp3[j * 512 + tid];
        wv2[2 * j]     = make_float2(t.x, t.y);
        wv2[2 * j + 1] = make_float2(t.z, t.w);
    }

    // ---- per-thread invariants ----
    const bool isCell = (ks < 2);
    const int  r      = ks & 1;
    float4 wqv = make_float4(0.f, 0.f, 0.f, 0.f);
    float bb = 0.f, cxr = 0.f;
    if (isCell) {
        wqv = *(const float4*)(Wq + h * 4);
        bb  = bq[h];
    }
    // q-tasks: one per quad at (tid&15)<4 -> 32 tasks spread over all 8 waves
    const bool isQ = (tid & 15) < 4;
    const int qi = tid >> 4;         // 0..31
    const int rq = qi & 1, qc = qi >> 1;        // qc = qg*4+qw
    const int qg = qc >> 2, qw = qc & 3;
    float qcoef = 1.f, qth3 = 0.f;
    float2 qw2[16] = {};
    if (isQ) {
        const float* thp = (qg == 0) ? thf : (qg == 1) ? thi : (qg == 2) ? thg : tho;
        qcoef = (qw < 3) ? cosf(thp[qw]) : 1.f;
        qth3  = thp[3];
        const float4* qp = (const float4*)(Whql + (size_t)qc * 128 + ks * 32);
        #pragma unroll
        for (int j = 0; j < 8; ++j) {
            float4 t = qp[j];
            qw2[2 * j]     = make_float2(t.x, t.y);
            qw2[2 * j + 1] = make_float2(t.z, t.w);
        }
    }
    if (isCell) {
        const float* hs = (t0 == 0) ? hx0 : stateH;
        const float* cs = (t0 == 0) ? cx0 : stateC;
        hL[r][hsk(h)] = hs[(size_t)(row0 + r) * HH + h];
        cxr           = cs[(size_t)(row0 + r) * HH + h];
    }
    __syncthreads();

    // incremental pointers (no per-step 64-bit muls)
    const float* zbase = Zx + (size_t)row0 * NCOL;            // += BB*NCOL per step
    float*       outp  = out + (((size_t)t0 * BB) + row0 + r) * HH + h;   // += BB*HH per step

    for (int tc = 0; tc < TC; ++tc) {
        // prefetch (latency hidden under GEMM)
        float zc0 = 0, zc1 = 0, zc2 = 0, zc3 = 0, zqv = 0;
        if (isCell) {
            const float* zp = zbase + (size_t)r * NCOL + h;
            zc0 = zp[0]; zc1 = zp[128]; zc2 = zp[256]; zc3 = zp[384];
        }
        if (isQ) zqv = zbase[(size_t)rq * NCOL + 512 + qc];

        // ---- h-GEMM: 4 gate-cols (own h) x 32 k x 2 rows, packed fp32 ----
        float2 aF0 = {}, aF1 = {}, aI0 = {}, aI1 = {}, aG0 = {}, aG1 = {}, aO0 = {}, aO1 = {};
        float2 qa2 = {};
        {
            const float4* h0p = (const float4*)&hL[0][40 * ks];
            const float4* h1p = (const float4*)&hL[1][40 * ks];
            const float4* hqp = (const float4*)&hL[rq][40 * ks];   // q row (masked lanes)
            #pragma unroll
            for (int k4 = 0; k4 < 8; ++k4) {
                float4 t0v = h0p[k4], t1v = h1p[k4];
                float2 h0a = make_float2(t0v.x, t0v.y), h0b = make_float2(t0v.z, t0v.w);
                float2 h1a = make_float2(t1v.x, t1v.y), h1b = make_float2(t1v.z, t1v.w);
                pkfma(aF0, wv2[k4 * 2],      h0a); pkfma(aF0, wv2[k4 * 2 + 1],      h0b);
                pkfma(aF1, wv2[k4 * 2],      h1a); pkfma(aF1, wv2[k4 * 2 + 1],      h1b);
                pkfma(aI0, wv2[16 + k4 * 2], h0a); pkfma(aI0, wv2[16 + k4 * 2 + 1], h0b);
                pkfma(aI1, wv2[16 + k4 * 2], h1a); pkfma(aI1, wv2[16 + k4 * 2 + 1], h1b);
                pkfma(aG0, wv2[32 + k4 * 2], h0a); pkfma(aG0, wv2[32 + k4 * 2 + 1], h0b);
                pkfma(aG1, wv2[32 + k4 * 2], h1a); pkfma(aG1, wv2[32 + k4 * 2 + 1], h1b);
                pkfma(aO0, wv2[48 + k4 * 2], h0a); pkfma(aO0, wv2[48 + k4 * 2 + 1], h0b);
                pkfma(aO1, wv2[48 + k4 * 2], h1a); pkfma(aO1, wv2[48 + k4 * 2 + 1], h1b);
                float4 tq = hqp[k4];
                float2 hqa = make_float2(tq.x, tq.y), hqb = make_float2(tq.z, tq.w);
                pkfma(qa2, qw2[k4 * 2], hqa); pkfma(qa2, qw2[k4 * 2 + 1], hqb);
            }
        }
        // combine packed halves, then in-quad DPP allreduce (VALU only)
        float sF0 = aF0.x + aF0.y, sF1 = aF1.x + aF1.y;
        float sI0 = aI0.x + aI0.y, sI1 = aI1.x + aI1.y;
        float sG0 = aG0.x + aG0.y, sG1 = aG1.x + aG1.y;
        float sO0 = aO0.x + aO0.y, sO1 = aO1.x + aO1.y;
        float qa  = qa2.x + qa2.y;
        DPPRED(sF0) DPPRED(sF1) DPPRED(sI0) DPPRED(sI1)
        DPPRED(sG0) DPPRED(sG1) DPPRED(sO0) DPPRED(sO1)
        DPPRED(qa)

        // ---- q-tasks: angle -> cosines published to LDS ----
        if (isQ) {
            float a = zqv + qa;
            float c = __cosf(a);
            float dval = (qw < 3) ? qcoef * c : __cosf(a + qth3);
            if (ks == 0) {
                cEd[rq][qc] = dval;
                cEc[rq][qc] = c;
            }
        }
        __syncthreads();   // cE* visible; all hL reads done

        // ---- fused cell update: assemble E from cosine prefix products ----
        if (isCell) {
            float pf = zc0 + (r ? sF1 : sF0);
            float pi = zc1 + (r ? sI1 : sI0);
            float pg = zc2 + (r ? sG1 : sG0);
            float po = zc3 + (r ? sO1 : sO0);
            float qz[4];
            #pragma unroll
            for (int g = 0; g < 4; ++g) {
                float4 dv = *(const float4*)&cEd[r][g * 4];
                float4 cv = *(const float4*)&cEc[r][g * 4];
                float c01  = cv.x * cv.y;
                float c012 = c01 * cv.z;
                qz[g] = fmaf(dv.x, wqv.x,
                        fmaf(dv.y * cv.x, wqv.y,
                        fmaf(dv.z * c01, wqv.z,
                        fmaf(dv.w * c012, wqv.w, bb))));
            }
            float f  = sigm(pf)   + sigm(qz[0]);
            float ii = sigm(pi)   + sigm(qz[1]);
            float gg = tanh_f(pg) + tanh_f(qz[2]);
            float oo = sigm(po)   + sigm(qz[3]);
            float cn = fmaf(f, cxr, ii * gg);
            cxr = cn;
            float hn = oo * tanh_f(cn);
            hL[r][hsk(h)] = hn;
            *outp = hn;
        }
        __syncthreads();   // h_{t+1} visible
        zbase += (size_t)BB * NCOL;
        outp  += (size_t)BB * HH;
    }

    if (isCell) {
        float hn = hL[r][hsk(h)];
        stateH[(size_t)(row0 + r) * HH + h] = hn;
        stateC[(size_t)(row0 + r) * HH + h] = cxr;
        if (t0 + TC == TT) {
            size_t base = (size_t)TT * BB * HH;
            out[base + (size_t)(row0 + r) * HH + h]                   = hn;
            out[base + (size_t)BB * HH + (size_t)(row0 + r) * HH + h] = cxr;
        }
    }
}

extern "C" void kernel_launch(void* const* d_in, const int* in_sizes, int n_in,
                              void* d_out, int out_size, void* d_ws, size_t ws_size,
                              hipStream_t stream) {
    const float* X   = (const float*)d_in[0];
    const float* hx0 = (const float*)d_in[1];
    const float* cx0 = (const float*)d_in[2];
    const float* Wf  = (const float*)d_in[3];
    const float* bf  = (const float*)d_in[4];
    const float* Wfq = (const float*)d_in[5];
    const float* bfq = (const float*)d_in[6];
    const float* thf = (const float*)d_in[7];
    const float* Wi  = (const float*)d_in[8];
    const float* bi  = (const float*)d_in[9];
    const float* Wiq = (const float*)d_in[10];
    const float* biq = (const float*)d_in[11];
    const float* thi = (const float*)d_in[12];
    const float* Wg  = (const float*)d_in[13];
    const float* bg  = (const float*)d_in[14];
    const float* Wgq = (const float*)d_in[15];
    const float* bgq = (const float*)d_in[16];
    const float* thg = (const float*)d_in[17];
    const float* Wo  = (const float*)d_in[18];
    const float* bo  = (const float*)d_in[19];
    const float* Woq = (const float*)d_in[20];
    const float* boq = (const float*)d_in[21];
    const float* tho = (const float*)d_in[22];
    const float* Wq  = (const float*)d_in[23];
    const float* bq  = (const float*)d_in[24];

    float* ws = (float*)d_ws;
    float* Wxp    = ws;                         // 528*128 = 67584
    float* Whr3   = Wxp + 528 * 128;            // 32*512*4 = 65536
    float* Whql   = Whr3 + 65536;               // 16*128 = 2048
    float* bcatp  = Whql + 2048;                // 576
    float* stateH = bcatp + NCPAD;              // 65536
    float* stateC = stateH + 512 * 128;         // 65536
    float* Zxb    = stateC + 512 * 128;

    size_t fixed_bytes = (size_t)(Zxb - ws) * sizeof(float);
    int TC = 256;
    while (TC > 4 && fixed_bytes + (size_t)TC * 512 * NCOL * 4 > ws_size) TC >>= 1;

    pack_weights<<<(NCOL * KK + 255) / 256, 256, 0, stream>>>(
        Wf, bf, Wfq, bfq, Wi, bi, Wiq, biq, Wg, bg, Wgq, bgq, Wo, bo, Woq, boq,
        Wxp, Whr3, Whql, bcatp);

    for (int t0 = 0; t0 < TT; t0 += TC) {
        xgemm<<<dim3(TC * 512 / P1_BM, NCPAD / P1_BN), 256, 0, stream>>>(
            X + (size_t)t0 * BB * DD, Wxp, bcatp, Zxb);
        qlstm_rec<<<256, 512, 0, stream>>>(
            Zxb, Whr3, Whql, hx0, cx0, stateH, stateC, Wq, bq,
            thf, thi, thg, tho, (float*)d_out, t0, TC);
    }
}

// Round 12
// 798.525 us; speedup vs baseline: 1.0490x; 1.0490x over previous
//
#include <hip/hip_runtime.h>
#include <cmath>

#define TT 256
#define BB 512
#define DD 128
#define HH 128
#define NCOL 528   // 4*H + 16 quantum-angle cols
#define KK 256
#define NCPAD 576  // 9 * 64

typedef float v2f __attribute__((ext_vector_type(2)));

// ---------------- weight pack ----------------
__global__ __launch_bounds__(256) void pack_weights(
    const float* __restrict__ Wf, const float* __restrict__ bf,
    const float* __restrict__ Wfq, const float* __restrict__ bfq,
    const float* __restrict__ Wi, const float* __restrict__ bi,
    const float* __restrict__ Wiq, const float* __restrict__ biq,
    const float* __restrict__ Wg, const float* __restrict__ bg,
    const float* __restrict__ Wgq, const float* __restrict__ bgq,
    const float* __restrict__ Wo, const float* __restrict__ bo,
    const float* __restrict__ Woq, const float* __restrict__ boq,
    float* __restrict__ Wxp, float* __restrict__ Whr3,
    float* __restrict__ Whql, float* __restrict__ bcat)
{
    int idx = blockIdx.x * blockDim.x + threadIdx.x;
    if (idx < NCOL * KK) {
        int c = idx >> 8, k = idx & 255;
        const float* srcW; int cl;
        if (c < 512) { int g = c >> 7; cl = c & 127;
            srcW = (g == 0) ? Wf : (g == 1) ? Wi : (g == 2) ? Wg : Wo; }
        else { int g = (c - 512) >> 2; cl = (c - 512) & 3;
            srcW = (g == 0) ? Wfq : (g == 1) ? Wiq : (g == 2) ? Wgq : Woq; }
        float v = srcW[(size_t)cl * KK + k];
        if (k < 128) Wxp[(size_t)c * 128 + k] = v;
        else {
            int kk = k - 128;
            if (c < 512) {
                int gate = c >> 7, hcol = c & 127;
                int t = hcol * 4 + (kk >> 5);
                int j = gate * 8 + ((kk >> 2) & 7);
                Whr3[((size_t)j * 512 + t) * 4 + (kk & 3)] = v;
            } else {
                Whql[(size_t)(c - 512) * 128 + kk] = v;
            }
        }
    }
    if (idx < NCPAD) {
        float b = 0.f;
        int c = idx;
        if (c < 512) { int g = c >> 7; int cl = c & 127;
            b = (g == 0) ? bf[cl] : (g == 1) ? bi[cl] : (g == 2) ? bg[cl] : bo[cl]; }
        else if (c < NCOL) { int g = (c - 512) >> 2; int cl = (c - 512) & 3;
            b = (g == 0) ? bfq[cl] : (g == 1) ? biq[cl] : (g == 2) ? bgq[cl] : boq[cl]; }
        bcat[c] = b;
    }
}

// ---------------- phase 1: Zx = X @ Wx^T + bcat  (M x 528, K=128) ----------------
#define P1_BM 128
#define P1_BN 64
#define ATP 132
#define BTP 68
__global__ __launch_bounds__(256, 3) void xgemm(
    const float* __restrict__ X, const float* __restrict__ Wxp,
    const float* __restrict__ bcat, float* __restrict__ Zx)
{
    __shared__ float At[64][ATP];
    __shared__ float Bt[64][BTP];
    const int tid = threadIdx.x;
    const int m0 = blockIdx.x * P1_BM;
    const int c0 = blockIdx.y * P1_BN;
    const int tm = tid >> 3;
    const int tn = tid & 7;
    float acc[4][8] = {};

    for (int khf = 0; khf < 2; ++khf) {
        #pragma unroll
        for (int j = 0; j < 8; ++j) {
            int fidx = tid + 256 * j;
            int m = fidx >> 4, k4 = (fidx & 15) * 4;
            float4 v = *(const float4*)(X + (size_t)(m0 + m) * 128 + khf * 64 + k4);
            At[k4 + 0][m] = v.x; At[k4 + 1][m] = v.y; At[k4 + 2][m] = v.z; At[k4 + 3][m] = v.w;
        }
        #pragma unroll
        for (int j = 0; j < 4; ++j) {
            int fidx = tid + 256 * j;
            int c = fidx >> 4, k4 = (fidx & 15) * 4;
            int cg = c0 + c;
            float4 v = make_float4(0.f, 0.f, 0.f, 0.f);
            if (cg < NCOL) v = *(const float4*)(Wxp + (size_t)cg * 128 + khf * 64 + k4);
            Bt[k4 + 0][c] = v.x; Bt[k4 + 1][c] = v.y; Bt[k4 + 2][c] = v.z; Bt[k4 + 3][c] = v.w;
        }
        __syncthreads();
        #pragma unroll 4
        for (int k = 0; k < 64; ++k) {
            float4 a  = *(const float4*)&At[k][tm * 4];
            float4 b0 = *(const float4*)&Bt[k][tn * 8];
            float4 b1 = *(const float4*)&Bt[k][tn * 8 + 4];
            float av[4] = {a.x, a.y, a.z, a.w};
            float bv[8] = {b0.x, b0.y, b0.z, b0.w, b1.x, b1.y, b1.z, b1.w};
            #pragma unroll
            for (int i = 0; i < 4; ++i)
                #pragma unroll
                for (int j = 0; j < 8; ++j)
                    acc[i][j] = fmaf(av[i], bv[j], acc[i][j]);
        }
        __syncthreads();
    }
    int c = c0 + tn * 8;
    if (c < NCOL) {
        float4 ba = *(const float4*)(bcat + c);
        float4 bb = *(const float4*)(bcat + c + 4);
        #pragma unroll
        for (int i = 0; i < 4; ++i) {
            int m = m0 + tm * 4 + i;
            float4 o0, o1;
            o0.x = acc[i][0] + ba.x; o0.y = acc[i][1] + ba.y;
            o0.z = acc[i][2] + ba.z; o0.w = acc[i][3] + ba.w;
            o1.x = acc[i][4] + bb.x; o1.y = acc[i][5] + bb.y;
            o1.z = acc[i][6] + bb.z; o1.w = acc[i][7] + bb.w;
            *(float4*)(Zx + (size_t)m * NCOL + c)     = o0;
            *(float4*)(Zx + (size_t)m * NCOL + c + 4) = o1;
        }
    }
}

// ---------------- phase 2: recurrence ----------------
__device__ __forceinline__ float sigm(float x) { return 1.0f / (1.0f + __expf(-x)); }
__device__ __forceinline__ float tanh_f(float x) {
    float e = __expf(2.f * x);
    return 1.f - 2.f / (e + 1.f);
}

// packed fp32 fma via compiler IR (emits v_pk_fma_f32, regalloc stays free)
#define PKFMA(acc, Wv, Hv) (acc) = __builtin_elementwise_fma((Wv), (Hv), (acc))

// in-quad allreduce via DPP quad_perm: 0xB1 = xor1, 0x4E = xor2
#define DPPRED(v) { \
    v += __int_as_float(__builtin_amdgcn_update_dpp(0, __float_as_int(v), 0xB1, 0xF, 0xF, true)); \
    v += __int_as_float(__builtin_amdgcn_update_dpp(0, __float_as_int(v), 0x4E, 0xF, 0xF, true)); }

// skewed h index: the 4 k-segments land on distinct bank quads
__device__ __forceinline__ int hsk(int k) { return k + 8 * (k >> 5); }  // max 151

// 512 threads; waves_per_eu(2,2): 256-VGPR cap.
__global__ __launch_bounds__(512)
__attribute__((amdgpu_waves_per_eu(2, 2)))
void qlstm_rec(
    const float* __restrict__ Zx,      // [TC][512][528]
    const float* __restrict__ Whr3,    // float4 [32][512]
    const float* __restrict__ Whql,    // [16][128]
    const float* __restrict__ hx0, const float* __restrict__ cx0,
    float* __restrict__ stateH, float* __restrict__ stateC,
    const float* __restrict__ Wq, const float* __restrict__ bq,
    const float* __restrict__ thf, const float* __restrict__ thi,
    const float* __restrict__ thg, const float* __restrict__ tho,
    float* __restrict__ out, int t0, int TC)
{
    __shared__ __align__(16) float hL[2][152];     // skewed
    __shared__ __align__(16) float cEd[2][20];     // per (r,qc): d-factor
    __shared__ __align__(16) float cEc[2][20];     // per (r,qc): raw cos

    const int tid  = threadIdx.x;
    const int row0 = blockIdx.x * 2;
    const int ks   = tid & 3;        // k-segment (32 k each)
    const int h    = tid >> 2;       // 0..127

    // ---- main weights: 64 v2f (128 regs), coalesced f4 loads ----
    const float4* Wp3 = (const float4*)Whr3;
    v2f wv2[64];
    #pragma unroll
    for (int j = 0; j < 32; ++j) {
        float4 t = Wp3[j * 512 + tid];
        wv2[2 * j]     = (v2f){t.x, t.y};
        wv2[2 * j + 1] = (v2f){t.z, t.w};
    }

    // ---- per-thread invariants ----
    const bool isCell = (ks < 2);
    const int  r      = ks & 1;
    float4 wqv = make_float4(0.f, 0.f, 0.f, 0.f);
    float bb = 0.f, cxr = 0.f;
    if (isCell) {
        wqv = *(const float4*)(Wq + h * 4);
        bb  = bq[h];
    }
    // q-tasks: one per quad at (tid&15)<4 -> 32 tasks over all 8 waves
    const bool isQ = (tid & 15) < 4;
    const int qi = tid >> 4;
    const int rq = qi & 1, qc = qi >> 1;
    const int qg = qc >> 2, qw = qc & 3;
    float qcoef = 1.f, qth3 = 0.f;
    v2f qw2[16] = {};
    if (isQ) {
        const float* thp = (qg == 0) ? thf : (qg == 1) ? thi : (qg == 2) ? thg : tho;
        qcoef = (qw < 3) ? cosf(thp[qw]) : 1.f;
        qth3  = thp[3];
        const float4* qp = (const float4*)(Whql + (size_t)qc * 128 + ks * 32);
        #pragma unroll
        for (int j = 0; j < 8; ++j) {
            float4 t = qp[j];
            qw2[2 * j]     = (v2f){t.x, t.y};
            qw2[2 * j + 1] = (v2f){t.z, t.w};
        }
    }
    if (isCell) {
        const float* hs = (t0 == 0) ? hx0 : stateH;
        const float* cs = (t0 == 0) ? cx0 : stateC;
        hL[r][hsk(h)] = hs[(size_t)(row0 + r) * HH + h];
        cxr           = cs[(size_t)(row0 + r) * HH + h];
    }
    __syncthreads();

    // loop-invariant LDS pointers
    const float4* h0p = (const float4*)&hL[0][40 * ks];
    const float4* h1p = (const float4*)&hL[1][40 * ks];
    const float4* hqp = (const float4*)&hL[rq][40 * ks];   // q row base (invariant)

    // incremental global pointers
    const float* zbase = Zx + (size_t)row0 * NCOL;
    float*       outp  = out + (((size_t)t0 * BB) + row0 + r) * HH + h;

    for (int tc = 0; tc < TC; ++tc) {
        // prefetch (latency hidden under GEMM)
        float zc0 = 0, zc1 = 0, zc2 = 0, zc3 = 0, zqv = 0;
        if (isCell) {
            const float* zp = zbase + (size_t)r * NCOL + h;
            zc0 = zp[0]; zc1 = zp[128]; zc2 = zp[256]; zc3 = zp[384];
        }
        if (isQ) zqv = zbase[(size_t)rq * NCOL + 512 + qc];

        // ---- h-GEMM: packed fp32; q-dot via direct LDS reads of own row ----
        v2f aF0 = {}, aF1 = {}, aI0 = {}, aI1 = {}, aG0 = {}, aG1 = {}, aO0 = {}, aO1 = {};
        v2f qa2 = {};
        #pragma unroll
        for (int k4 = 0; k4 < 8; ++k4) {
            float4 t0v = h0p[k4], t1v = h1p[k4], tqv = hqp[k4];
            v2f h0a = (v2f){t0v.x, t0v.y}, h0b = (v2f){t0v.z, t0v.w};
            v2f h1a = (v2f){t1v.x, t1v.y}, h1b = (v2f){t1v.z, t1v.w};
            v2f hqa = (v2f){tqv.x, tqv.y}, hqb = (v2f){tqv.z, tqv.w};
            PKFMA(aF0, wv2[k4 * 2],      h0a); PKFMA(aF0, wv2[k4 * 2 + 1],      h0b);
            PKFMA(aF1, wv2[k4 * 2],      h1a); PKFMA(aF1, wv2[k4 * 2 + 1],      h1b);
            PKFMA(aI0, wv2[16 + k4 * 2], h0a); PKFMA(aI0, wv2[16 + k4 * 2 + 1], h0b);
            PKFMA(aI1, wv2[16 + k4 * 2], h1a); PKFMA(aI1, wv2[16 + k4 * 2 + 1], h1b);
            PKFMA(aG0, wv2[32 + k4 * 2], h0a); PKFMA(aG0, wv2[32 + k4 * 2 + 1], h0b);
            PKFMA(aG1, wv2[32 + k4 * 2], h1a); PKFMA(aG1, wv2[32 + k4 * 2 + 1], h1b);
            PKFMA(aO0, wv2[48 + k4 * 2], h0a); PKFMA(aO0, wv2[48 + k4 * 2 + 1], h0b);
            PKFMA(aO1, wv2[48 + k4 * 2], h1a); PKFMA(aO1, wv2[48 + k4 * 2 + 1], h1b);
            PKFMA(qa2, qw2[k4 * 2],      hqa); PKFMA(qa2, qw2[k4 * 2 + 1],      hqb);
        }
        // combine packed halves, then in-quad DPP allreduce
        float sF0 = aF0.x + aF0.y, sF1 = aF1.x + aF1.y;
        float sI0 = aI0.x + aI0.y, sI1 = aI1.x + aI1.y;
        float sG0 = aG0.x + aG0.y, sG1 = aG1.x + aG1.y;
        float sO0 = aO0.x + aO0.y, sO1 = aO1.x + aO1.y;
        float qa  = qa2.x + qa2.y;
        DPPRED(sF0) DPPRED(sF1) DPPRED(sI0) DPPRED(sI1)
        DPPRED(sG0) DPPRED(sG1) DPPRED(sO0) DPPRED(sO1)
        DPPRED(qa)

        // ---- q-tasks: angle -> cosines published to LDS ----
        if (isQ) {
            float a = zqv + qa;
            float c = __cosf(a);
            float dval = (qw < 3) ? qcoef * c : __cosf(a + qth3);
            if (ks == 0) {
                cEd[rq][qc] = dval;
                cEc[rq][qc] = c;
            }
        }
        __syncthreads();   // cE* visible; all hL reads done

        // ---- fused cell update ----
        if (isCell) {
            float pf = zc0 + (r ? sF1 : sF0);
            float pi = zc1 + (r ? sI1 : sI0);
            float pg = zc2 + (r ? sG1 : sG0);
            float po = zc3 + (r ? sO1 : sO0);
            float qz[4];
            #pragma unroll
            for (int g = 0; g < 4; ++g) {
                float4 dv = *(const float4*)&cEd[r][g * 4];
                float4 cv = *(const float4*)&cEc[r][g * 4];
                float c01  = cv.x * cv.y;
                float c012 = c01 * cv.z;
                qz[g] = fmaf(dv.x, wqv.x,
                        fmaf(dv.y * cv.x, wqv.y,
                        fmaf(dv.z * c01, wqv.z,
                        fmaf(dv.w * c012, wqv.w, bb))));
            }
            float f  = sigm(pf)   + sigm(qz[0]);
            float ii = sigm(pi)   + sigm(qz[1]);
            float gg = tanh_f(pg) + tanh_f(qz[2]);
            float oo = sigm(po)   + sigm(qz[3]);
            float cn = fmaf(f, cxr, ii * gg);
            cxr = cn;
            float hn = oo * tanh_f(cn);
            hL[r][hsk(h)] = hn;
            *outp = hn;
        }
        __syncthreads();   // h_{t+1} visible
        zbase += (size_t)BB * NCOL;
        outp  += (size_t)BB * HH;
    }

    if (isCell) {
        float hn = hL[r][hsk(h)];
        stateH[(size_t)(row0 + r) * HH + h] = hn;
        stateC[(size_t)(row0 + r) * HH + h] = cxr;
        if (t0 + TC == TT) {
            size_t base = (size_t)TT * BB * HH;
            out[base + (size_t)(row0 + r) * HH + h]                   = hn;
            out[base + (size_t)BB * HH + (size_t)(row0 + r) * HH + h] = cxr;
        }
    }
}

extern "C" void kernel_launch(void* const* d_in, const int* in_sizes, int n_in,
                              void* d_out, int out_size, void* d_ws, size_t ws_size,
                              hipStream_t stream) {
    const float* X   = (const float*)d_in[0];
    const float* hx0 = (const float*)d_in[1];
    const float* cx0 = (const float*)d_in[2];
    const float* Wf  = (const float*)d_in[3];
    const float* bf  = (const float*)d_in[4];
    const float* Wfq = (const float*)d_in[5];
    const float* bfq = (const float*)d_in[6];
    const float* thf = (const float*)d_in[7];
    const float* Wi  = (const float*)d_in[8];
    const float* bi  = (const float*)d_in[9];
    const float* Wiq = (const float*)d_in[10];
    const float* biq = (const float*)d_in[11];
    const float* thi = (const float*)d_in[12];
    const float* Wg  = (const float*)d_in[13];
    const float* bg  = (const float*)d_in[14];
    const float* Wgq = (const float*)d_in[15];
    const float* bgq = (const float*)d_in[16];
    const float* thg = (const float*)d_in[17];
    const float* Wo  = (const float*)d_in[18];
    const float* bo  = (const float*)d_in[19];
    const float* Woq = (const float*)d_in[20];
    const float* boq = (const float*)d_in[21];
    const float* tho = (const float*)d_in[22];
    const float* Wq  = (const float*)d_in[23];
    const float* bq  = (const float*)d_in[24];

    float* ws = (float*)d_ws;
    float* Wxp    = ws;                         // 528*128 = 67584
    float* Whr3   = Wxp + 528 * 128;            // 32*512*4 = 65536
    float* Whql   = Whr3 + 65536;               // 16*128 = 2048
    float* bcatp  = Whql + 2048;                // 576
    float* stateH = bcatp + NCPAD;              // 65536
    float* stateC = stateH + 512 * 128;         // 65536
    float* Zxb    = stateC + 512 * 128;

    size_t fixed_bytes = (size_t)(Zxb - ws) * sizeof(float);
    int TC = 256;
    while (TC > 4 && fixed_bytes + (size_t)TC * 512 * NCOL * 4 > ws_size) TC >>= 1;

    pack_weights<<<(NCOL * KK + 255) / 256, 256, 0, stream>>>(
        Wf, bf, Wfq, bfq, Wi, bi, Wiq, biq, Wg, bg, Wgq, bgq, Wo, bo, Woq, boq,
        Wxp, Whr3, Whql, bcatp);

    for (int t0 = 0; t0 < TT; t0 += TC) {
        xgemm<<<dim3(TC * 512 / P1_BM, NCPAD / P1_BN), 256, 0, stream>>>(
            X + (size_t)t0 * BB * DD, Wxp, bcatp, Zxb);
        qlstm_rec<<<256, 512, 0, stream>>>(
            Zxb, Whr3, Whql, hx0, cx0, stateH, stateC, Wq, bq,
            thf, thi, thg, tho, (float*)d_out, t0, TC);
    }
}